// Round 8
// baseline (1164.050 us; speedup 1.0000x reference)
//
#include <hip/hip_runtime.h>
#include <stdint.h>

#define T_TOK 4096
#define HID   2048
#define FF    1408
#define NE    8
#define SLOT  65536            // one K-tile: A 32KB + B 32KB
#define BREG  32768            // B region offset within slot
#define NT1   (HID / 64)       // 32 K-tiles gemm1
#define NT2   (FF / 64)        // 22 K-tiles gemm2

typedef __attribute__((ext_vector_type(8))) short short8;
typedef __attribute__((ext_vector_type(4))) float f32x4;

__device__ inline unsigned short f2bf(float f) {
  uint32_t u = __builtin_bit_cast(uint32_t, f);
  u += 0x7fffu + ((u >> 16) & 1u);   // RNE
  return (unsigned short)(u >> 16);
}

__device__ inline uint32_t cvt_pk(float a, float b) {
  uint32_t r;
  asm("v_cvt_pk_bf16_f32 %0, %1, %2" : "=v"(r) : "v"(a), "v"(b));
  return r;
}

// async global->LDS DMA, 16B/lane; LDS dest linear (base + tid*16)
__device__ inline void gload16(const void* g, void* l) {
  __builtin_amdgcn_global_load_lds(
      (const __attribute__((address_space(1))) unsigned int*)g,
      (__attribute__((address_space(3))) unsigned int*)l, 16, 0, 0);
}

__device__ inline void vm0_barrier() {
  asm volatile("s_waitcnt vmcnt(0)" ::: "memory");
  __builtin_amdgcn_s_barrier();
  asm volatile("" ::: "memory");
}

// ---------------- router: per-token softmax + top2 ----------------
__global__ __launch_bounds__(256) void route_kernel(const float* __restrict__ logits,
                                                    int2* __restrict__ eids,
                                                    float2* __restrict__ ecfs) {
  int t = blockIdx.x * 256 + threadIdx.x;
  const float4* lp = (const float4*)(logits + (size_t)t * NE);
  float4 a = lp[0], b = lp[1];
  float l[8] = {a.x, a.y, a.z, a.w, b.x, b.y, b.z, b.w};
  float mx = l[0];
#pragma unroll
  for (int i = 1; i < 8; ++i) mx = fmaxf(mx, l[i]);
  float s = 0.f, p[8];
#pragma unroll
  for (int i = 0; i < 8; ++i) { p[i] = __expf(l[i] - mx); s += p[i]; }
  float inv = 1.f / s;
  int e0 = 0;
#pragma unroll
  for (int i = 1; i < 8; ++i) if (l[i] > l[e0]) e0 = i;
  int e1 = (e0 == 0) ? 1 : 0;
#pragma unroll
  for (int i = 0; i < 8; ++i) if (i != e0 && l[i] > l[e1]) e1 = i;
  eids[t] = make_int2(e0, e1);
  ecfs[t] = make_float2(p[e0] * inv, p[e1] * inv);
}

// ------------- deterministic per-expert compaction (8 blocks) -------------
__global__ __launch_bounds__(256) void compact_kernel(const int2* __restrict__ eids,
                                                      const float2* __restrict__ ecfs,
                                                      int* __restrict__ tok,
                                                      float* __restrict__ coef,
                                                      int* __restrict__ rowptr) {
  int e = blockIdx.x, tid = threadIdx.x;
  __shared__ int hist[8];
  __shared__ int wsum[4];
  __shared__ int runv;
  if (tid < 8) hist[tid] = 0;
  __syncthreads();
  for (int t = tid; t < T_TOK; t += 256) {
    int2 ei = eids[t];
    atomicAdd(&hist[ei.x], 1);
    atomicAdd(&hist[ei.y], 1);
  }
  __syncthreads();
  int off = 0;
  for (int j = 0; j < e; ++j) off += hist[j];
  if (tid == 0) {
    runv = 0;
    if (e == 0) rowptr[0] = 0;
    rowptr[e + 1] = off + hist[e];
  }
  __syncthreads();
  int wave = tid >> 6, lane = tid & 63;
  for (int c = 0; c < T_TOK; c += 256) {
    int t = c + tid;
    int2 ei = eids[t];
    float2 cf = ecfs[t];
    bool fl = false; float cv = 0.f;
    if (ei.x == e)      { fl = true; cv = cf.x; }
    else if (ei.y == e) { fl = true; cv = cf.y; }
    unsigned long long m = __ballot(fl);
    if (lane == 0) wsum[wave] = __popcll(m);
    __syncthreads();
    int woff = runv;
    for (int wv = 0; wv < wave; ++wv) woff += wsum[wv];
    int pos = off + woff + __popcll(m & ((1ull << lane) - 1ull));
    if (fl) { tok[pos] = t; coef[pos] = cv; }
    __syncthreads();
    if (tid == 0) runv += wsum[0] + wsum[1] + wsum[2] + wsum[3];
    __syncthreads();
  }
}

// ---------------- X f32 -> bf16 ----------------
__global__ __launch_bounds__(256) void cvtx_kernel(const float* __restrict__ x,
                                                   unsigned short* __restrict__ xb) {
  int i = blockIdx.x * 256 + threadIdx.x;  // 4 elems each
  float4 v = ((const float4*)x)[i];
  uint2 o;
  o.x = cvt_pk(v.x, v.y);
  o.y = cvt_pk(v.z, v.w);
  ((uint2*)xb)[i] = o;
}

// ------- weight convert+transpose: in[s][R][C] f32 -> out[s][C][R] bf16 -------
__global__ __launch_bounds__(256) void wcvt_kernel(const float* __restrict__ in,
                                                   unsigned short* __restrict__ out,
                                                   int R, int C) {
  __shared__ unsigned short t[64][72];
  const float* ip = in + ((size_t)blockIdx.z * R + blockIdx.y * 64) * C + blockIdx.x * 64;
  int tid = threadIdx.x;
  int r = tid >> 2, cg = (tid & 3) * 16;
  const float* rp = ip + (size_t)r * C + cg;
#pragma unroll
  for (int j = 0; j < 4; ++j) {
    float4 v = *(const float4*)(rp + j * 4);
    int c = cg + j * 4;
    t[c + 0][r] = f2bf(v.x);
    t[c + 1][r] = f2bf(v.y);
    t[c + 2][r] = f2bf(v.z);
    t[c + 3][r] = f2bf(v.w);
  }
  __syncthreads();
  int cr = tid >> 2, kg = (tid & 3) * 16;
  unsigned short* op = out + ((size_t)blockIdx.z * C + blockIdx.x * 64 + cr) * R +
                       blockIdx.y * 64 + kg;
  *(short8*)op = *(const short8*)&t[cr][kg];
  *(short8*)(op + 8) = *(const short8*)&t[cr][kg + 8];
}

// One MFMA phase: 2 mi rows x 4 ni x 2 ks = 16 MFMA, clustered behind a barrier.
#define PHASE(S, q) do {                                                      \
    short8 aA = *(const short8*)((S) + aoff[2*(q)]);                          \
    short8 aB = *(const short8*)((S) + (aoff[2*(q)] ^ 64));                   \
    short8 aC = *(const short8*)((S) + aoff[2*(q)+1]);                        \
    short8 aD = *(const short8*)((S) + (aoff[2*(q)+1] ^ 64));                 \
    __builtin_amdgcn_s_barrier();                                             \
    __builtin_amdgcn_s_setprio(1);                                            \
    _Pragma("unroll")                                                         \
    for (int ni = 0; ni < 4; ++ni) {                                          \
      acc[2*(q)][ni]   = __builtin_amdgcn_mfma_f32_16x16x32_bf16(aA, bb[ni][0], acc[2*(q)][ni], 0, 0, 0);   \
      acc[2*(q)][ni]   = __builtin_amdgcn_mfma_f32_16x16x32_bf16(aB, bb[ni][1], acc[2*(q)][ni], 0, 0, 0);   \
      acc[2*(q)+1][ni] = __builtin_amdgcn_mfma_f32_16x16x32_bf16(aC, bb[ni][0], acc[2*(q)+1][ni], 0, 0, 0); \
      acc[2*(q)+1][ni] = __builtin_amdgcn_mfma_f32_16x16x32_bf16(aD, bb[ni][1], acc[2*(q)+1][ni], 0, 0, 0); \
    }                                                                         \
    __builtin_amdgcn_s_setprio(0);                                            \
  } while (0)

// ======== GEMM1: 256x256x64, 8 waves, phase-split schedule, DMA dbuf ========
// h = silu(X W1g) * (X W1u). B rows interleave proj at 16-row granularity:
// row r -> proj=(r>>4)&1, f_local=(r&15)+16*(r>>5) -> SwiGLU thread-local.
__global__ __launch_bounds__(512, 2) void gemm1_kernel(const unsigned short* __restrict__ Xb,
                                                       const unsigned short* __restrict__ w1t,
                                                       const int* __restrict__ tok,
                                                       const int* __restrict__ rowptr,
                                                       unsigned short* __restrict__ hbuf) {
  int mtile = blockIdx.x, ntile = blockIdx.y, e = blockIdx.z;
  int base = rowptr[e], cnt = rowptr[e + 1] - base;
  if (mtile * 256 >= cnt) return;
  __shared__ char smem[2 * SLOT];           // 128KB: 2 K-tile slots (A 32K + B 32K)
  int tid = threadIdx.x, lane = tid & 63, wave = tid >> 6;
  int wm = wave >> 2, wn = wave & 3;        // 2 x 4 -> wave tile 128M x 64N

  // staging: call c covers rows 64c+(tid>>3), chunk p=tid&7; linear LDS dest tid*16;
  // global source pre-swizzled: data chunk = p ^ (row&7)
  int p = tid & 7, rr = tid >> 3;
  const unsigned short* gA[4];
  const unsigned short* gB[4];
#pragma unroll
  for (int c = 0; c < 4; ++c) {
    int row = 64 * c + rr;
    int ch = p ^ (row & 7);
    int slot = min(mtile * 256 + row, cnt - 1);
    gA[c] = Xb + (size_t)tok[base + slot] * HID + ch * 8;
    int proj = (row >> 4) & 1;
    int fg = ntile * 128 + (row & 15) + 16 * (row >> 5);
    gB[c] = w1t + ((size_t)(e * 2 + proj) * FF + fg) * HID + ch * 8;
  }
  int ldst = tid * 16;

#define STG1(sb, k0) do {                                         \
    _Pragma("unroll") for (int c = 0; c < 4; ++c)                 \
      gload16(gA[c] + (k0), smem + (sb) + c * 8192 + ldst);       \
    _Pragma("unroll") for (int c = 0; c < 4; ++c)                 \
      gload16(gB[c] + (k0), smem + (sb) + BREG + c * 8192 + ldst);\
  } while (0)

  // fragment read offsets (swizzled; ks=1 frag = addr ^ 64)
  int g = lane >> 4, j = lane & 15;
  int aoff[8], boff[4];
#pragma unroll
  for (int mi = 0; mi < 8; ++mi) {
    int row = wm * 128 + mi * 16 + j;
    aoff[mi] = row * 128 + ((g ^ (row & 7)) << 4);
  }
#pragma unroll
  for (int ni = 0; ni < 4; ++ni) {
    int row = wn * 64 + ni * 16 + j;
    boff[ni] = BREG + row * 128 + ((g ^ (row & 7)) << 4);
  }

  const f32x4 vz = {0.f, 0.f, 0.f, 0.f};
  f32x4 acc[8][4];
#pragma unroll
  for (int mi = 0; mi < 8; ++mi)
#pragma unroll
    for (int ni = 0; ni < 4; ++ni) acc[mi][ni] = vz;

  STG1(0, 0);
  vm0_barrier();                 // one-time prologue drain

  for (int t = 0; t < NT1; ++t) {
    char* S = smem + (t & 1) * SLOT;
    if (t + 1 < NT1) STG1(((t + 1) & 1) * SLOT, (t + 1) * 64);  // front-loaded stage
    short8 bb[4][2];
#pragma unroll
    for (int ni = 0; ni < 4; ++ni) {
      bb[ni][0] = *(const short8*)(S + boff[ni]);
      bb[ni][1] = *(const short8*)(S + (boff[ni] ^ 64));
    }
    PHASE(S, 0);
    PHASE(S, 1);
    PHASE(S, 2);
    PHASE(S, 3);
    vm0_barrier();               // seal t+1 (issued 4 phases ago -> nearly free)
  }
#undef STG1

  // epilogue: SwiGLU thread-local; gate = acc[mi][2pr], up = acc[mi][2pr+1]
  int fb0 = ntile * 128 + j;
#pragma unroll
  for (int mi = 0; mi < 8; ++mi) {
#pragma unroll
    for (int i = 0; i < 4; ++i) {
      int r = wm * 128 + mi * 16 + g * 4 + i;
      int slot = mtile * 256 + r;
      if (slot < cnt) {
        size_t hrow = (size_t)(base + slot) * FF + fb0;
#pragma unroll
        for (int pr = 0; pr < 2; ++pr) {
          float gg = acc[mi][2 * pr][i], uu = acc[mi][2 * pr + 1][i];
          float hv = gg / (1.f + __expf(-gg)) * uu;
          hbuf[hrow + 16 * (2 * wn + pr)] = f2bf(hv);
        }
      }
    }
  }
}

// ======== GEMM2: 256x256x64, 8 waves, phase-split schedule, DMA dbuf ========
// out += coef * (h W2); B = w2t[e][h][f] bf16 (k = f contiguous).
__global__ __launch_bounds__(512, 2) void gemm2_kernel(const unsigned short* __restrict__ hbuf,
                                                       const unsigned short* __restrict__ w2t,
                                                       const int* __restrict__ tok,
                                                       const float* __restrict__ coef,
                                                       const int* __restrict__ rowptr,
                                                       float* __restrict__ out) {
  int mtile = blockIdx.x, ntile = blockIdx.y, e = blockIdx.z;
  int base = rowptr[e], cnt = rowptr[e + 1] - base;
  if (mtile * 256 >= cnt) return;
  __shared__ char smem[2 * SLOT];
  int tid = threadIdx.x, lane = tid & 63, wave = tid >> 6;
  int wm = wave >> 2, wn = wave & 3;

  int p = tid & 7, rr = tid >> 3;
  const unsigned short* gA[4];
  const unsigned short* gB[4];
#pragma unroll
  for (int c = 0; c < 4; ++c) {
    int row = 64 * c + rr;
    int ch = p ^ (row & 7);
    int slot = min(mtile * 256 + row, cnt - 1);
    gA[c] = hbuf + (size_t)(base + slot) * FF + ch * 8;
    gB[c] = w2t + ((size_t)e * HID + ntile * 256 + row) * FF + ch * 8;
  }
  int ldst = tid * 16;

#define STG2(sb, k0) do {                                         \
    _Pragma("unroll") for (int c = 0; c < 4; ++c)                 \
      gload16(gA[c] + (k0), smem + (sb) + c * 8192 + ldst);       \
    _Pragma("unroll") for (int c = 0; c < 4; ++c)                 \
      gload16(gB[c] + (k0), smem + (sb) + BREG + c * 8192 + ldst);\
  } while (0)

  int g = lane >> 4, j = lane & 15;
  int aoff[8], boff[4];
#pragma unroll
  for (int mi = 0; mi < 8; ++mi) {
    int row = wm * 128 + mi * 16 + j;
    aoff[mi] = row * 128 + ((g ^ (row & 7)) << 4);
  }
#pragma unroll
  for (int ni = 0; ni < 4; ++ni) {
    int row = wn * 64 + ni * 16 + j;
    boff[ni] = BREG + row * 128 + ((g ^ (row & 7)) << 4);
  }

  const f32x4 vz = {0.f, 0.f, 0.f, 0.f};
  f32x4 acc[8][4];
#pragma unroll
  for (int mi = 0; mi < 8; ++mi)
#pragma unroll
    for (int ni = 0; ni < 4; ++ni) acc[mi][ni] = vz;

  STG2(0, 0);
  vm0_barrier();

  for (int t = 0; t < NT2; ++t) {
    char* S = smem + (t & 1) * SLOT;
    if (t + 1 < NT2) STG2(((t + 1) & 1) * SLOT, (t + 1) * 64);
    short8 bb[4][2];
#pragma unroll
    for (int ni = 0; ni < 4; ++ni) {
      bb[ni][0] = *(const short8*)(S + boff[ni]);
      bb[ni][1] = *(const short8*)(S + (boff[ni] ^ 64));
    }
    PHASE(S, 0);
    PHASE(S, 1);
    PHASE(S, 2);
    PHASE(S, 3);
    vm0_barrier();
  }
#undef STG2

  // epilogue: scatter with coef via atomics (tok/coef from global, L2-broadcast)
  int nb = ntile * 256 + wn * 64 + j;
#pragma unroll
  for (int mi = 0; mi < 8; ++mi) {
#pragma unroll
    for (int i = 0; i < 4; ++i) {
      int r = wm * 128 + mi * 16 + g * 4 + i;
      int slot = mtile * 256 + r;
      if (slot < cnt) {
        int tk = tok[base + slot];
        float cf = coef[base + slot];
        float* op = out + (size_t)tk * HID + nb;
#pragma unroll
        for (int ni = 0; ni < 4; ++ni)
          unsafeAtomicAdd(op + ni * 16, cf * acc[mi][ni][i]);
      }
    }
  }
}

extern "C" void kernel_launch(void* const* d_in, const int* in_sizes, int n_in,
                              void* d_out, int out_size, void* d_ws, size_t ws_size,
                              hipStream_t stream) {
  const float* X  = (const float*)d_in[0];
  const float* RL = (const float*)d_in[1];
  const float* W1 = (const float*)d_in[2];
  const float* W2 = (const float*)d_in[3];
  float* out = (float*)d_out;

  const size_t OFF_EIDS = 4096;
  const size_t OFF_ECFS = 36864;
  const size_t OFF_TOK  = 69632;
  const size_t OFF_COEF = 102400;
  const size_t OFF_XB   = 135168;
  const size_t OFF_H    = 16912384;
  const size_t OFF_W1T  = 39981056;
  const size_t OFF_W2T  = 132255744;
  const size_t TOTAL2   = 178393088;
  if (ws_size < TOTAL2 || n_in < 4) return;

  char* w = (char*)d_ws;
  int*    rowptr = (int*)w;
  int2*   eids   = (int2*)(w + OFF_EIDS);
  float2* ecfs   = (float2*)(w + OFF_ECFS);
  int*    tok    = (int*)(w + OFF_TOK);
  float*  coef   = (float*)(w + OFF_COEF);
  unsigned short* Xb   = (unsigned short*)(w + OFF_XB);
  unsigned short* hbuf = (unsigned short*)(w + OFF_H);
  unsigned short* w1t  = (unsigned short*)(w + OFF_W1T);
  unsigned short* w2t  = (unsigned short*)(w + OFF_W2T);

  hipMemsetAsync(d_out, 0, (size_t)T_TOK * HID * sizeof(float), stream);
  route_kernel<<<T_TOK / 256, 256, 0, stream>>>(RL, eids, ecfs);
  compact_kernel<<<NE, 256, 0, stream>>>(eids, ecfs, tok, coef, rowptr);
  cvtx_kernel<<<(T_TOK * HID / 4) / 256, 256, 0, stream>>>(X, Xb);
  // w1[e*2+g][k=2048][f=1408] -> w1t[e*2+g][f][k]
  wcvt_kernel<<<dim3(FF / 64, HID / 64, NE * 2), 256, 0, stream>>>(W1, w1t, HID, FF);
  // w2[e][f=1408][h=2048] -> w2t[e][h][f]
  wcvt_kernel<<<dim3(HID / 64, FF / 64, NE), 256, 0, stream>>>(W2, w2t, FF, HID);
  gemm1_kernel<<<dim3(32, FF / 128, NE), 512, 0, stream>>>(Xb, w1t, tok, rowptr, hbuf);
  gemm2_kernel<<<dim3(32, HID / 256, NE), 512, 0, stream>>>(hbuf, w2t, tok, coef, rowptr, out);
}

// Round 9
// 344.562 us; speedup vs baseline: 3.3783x; 3.3783x over previous
//
#include <hip/hip_runtime.h>
#include <stdint.h>

#define T_TOK 4096
#define HID   2048
#define FF    1408
#define NE    8
#define BUF   16384            // one pipeline stage: A 8KB + B 8KB
#define NT1   (HID / 32)       // 64 K-steps gemm1
#define NT2   (FF / 32)        // 44 K-steps gemm2

typedef __attribute__((ext_vector_type(8))) short short8;
typedef __attribute__((ext_vector_type(4))) float f32x4;

__device__ inline unsigned short f2bf(float f) {
  uint32_t u = __builtin_bit_cast(uint32_t, f);
  u += 0x7fffu + ((u >> 16) & 1u);   // RNE
  return (unsigned short)(u >> 16);
}

__device__ inline uint32_t cvt_pk(float a, float b) {
  uint32_t r;
  asm("v_cvt_pk_bf16_f32 %0, %1, %2" : "=v"(r) : "v"(a), "v"(b));
  return r;
}

// async global->LDS DMA, 16B/lane; LDS dest = wave-uniform base + lane*16 (linear)
__device__ inline void gload16(const void* g, void* l) {
  __builtin_amdgcn_global_load_lds(
      (const __attribute__((address_space(1))) unsigned int*)g,
      (__attribute__((address_space(3))) unsigned int*)l, 16, 0, 0);
}

// counted waits (T4): keep newest loads IN FLIGHT across the barrier.
__device__ inline void wait8_barrier() {
  asm volatile("s_waitcnt vmcnt(8)" ::: "memory");
  __builtin_amdgcn_s_barrier();
  asm volatile("" ::: "memory");
}
__device__ inline void wait4_barrier() {
  asm volatile("s_waitcnt vmcnt(4)" ::: "memory");
  __builtin_amdgcn_s_barrier();
  asm volatile("" ::: "memory");
}
__device__ inline void wait0_barrier() {
  asm volatile("s_waitcnt vmcnt(0)" ::: "memory");
  __builtin_amdgcn_s_barrier();
  asm volatile("" ::: "memory");
}

// ---------------- router: per-token softmax + top2 ----------------
__global__ __launch_bounds__(256) void route_kernel(const float* __restrict__ logits,
                                                    int2* __restrict__ eids,
                                                    float2* __restrict__ ecfs) {
  int t = blockIdx.x * 256 + threadIdx.x;
  const float4* lp = (const float4*)(logits + (size_t)t * NE);
  float4 a = lp[0], b = lp[1];
  float l[8] = {a.x, a.y, a.z, a.w, b.x, b.y, b.z, b.w};
  float mx = l[0];
#pragma unroll
  for (int i = 1; i < 8; ++i) mx = fmaxf(mx, l[i]);
  float s = 0.f, p[8];
#pragma unroll
  for (int i = 0; i < 8; ++i) { p[i] = __expf(l[i] - mx); s += p[i]; }
  float inv = 1.f / s;
  int e0 = 0;
#pragma unroll
  for (int i = 1; i < 8; ++i) if (l[i] > l[e0]) e0 = i;
  int e1 = (e0 == 0) ? 1 : 0;
#pragma unroll
  for (int i = 0; i < 8; ++i) if (i != e0 && l[i] > l[e1]) e1 = i;
  eids[t] = make_int2(e0, e1);
  ecfs[t] = make_float2(p[e0] * inv, p[e1] * inv);
}

// ------------- deterministic per-expert compaction (8 blocks) -------------
// also writes inverse map invm[2*t + k] = slot position (k: 0=primary expert)
__global__ __launch_bounds__(256) void compact_kernel(const int2* __restrict__ eids,
                                                      const float2* __restrict__ ecfs,
                                                      int* __restrict__ tok,
                                                      float* __restrict__ coef,
                                                      int* __restrict__ rowptr,
                                                      int* __restrict__ invm) {
  int e = blockIdx.x, tid = threadIdx.x;
  __shared__ int hist[8];
  __shared__ int wsum[4];
  __shared__ int runv;
  if (tid < 8) hist[tid] = 0;
  __syncthreads();
  for (int t = tid; t < T_TOK; t += 256) {
    int2 ei = eids[t];
    atomicAdd(&hist[ei.x], 1);
    atomicAdd(&hist[ei.y], 1);
  }
  __syncthreads();
  int off = 0;
  for (int j = 0; j < e; ++j) off += hist[j];
  if (tid == 0) {
    runv = 0;
    if (e == 0) rowptr[0] = 0;
    rowptr[e + 1] = off + hist[e];
  }
  __syncthreads();
  int wave = tid >> 6, lane = tid & 63;
  for (int c = 0; c < T_TOK; c += 256) {
    int t = c + tid;
    int2 ei = eids[t];
    float2 cf = ecfs[t];
    bool fl = false; float cv = 0.f; int ks = 0;
    if (ei.x == e)      { fl = true; cv = cf.x; ks = 0; }
    else if (ei.y == e) { fl = true; cv = cf.y; ks = 1; }
    unsigned long long m = __ballot(fl);
    if (lane == 0) wsum[wave] = __popcll(m);
    __syncthreads();
    int woff = runv;
    for (int wv = 0; wv < wave; ++wv) woff += wsum[wv];
    int pos = off + woff + __popcll(m & ((1ull << lane) - 1ull));
    if (fl) { tok[pos] = t; coef[pos] = cv; invm[2 * t + ks] = pos; }
    __syncthreads();
    if (tid == 0) runv += wsum[0] + wsum[1] + wsum[2] + wsum[3];
    __syncthreads();
  }
}

// ---------------- X f32 -> bf16 ----------------
__global__ __launch_bounds__(256) void cvtx_kernel(const float* __restrict__ x,
                                                   unsigned short* __restrict__ xb) {
  int i = blockIdx.x * 256 + threadIdx.x;  // 4 elems each
  float4 v = ((const float4*)x)[i];
  uint2 o;
  o.x = cvt_pk(v.x, v.y);
  o.y = cvt_pk(v.z, v.w);
  ((uint2*)xb)[i] = o;
}

// ------- weight convert+transpose: in[s][R][C] f32 -> out[s][C][R] bf16 -------
__global__ __launch_bounds__(256) void wcvt_kernel(const float* __restrict__ in,
                                                   unsigned short* __restrict__ out,
                                                   int R, int C) {
  __shared__ unsigned short t[64][72];
  const float* ip = in + ((size_t)blockIdx.z * R + blockIdx.y * 64) * C + blockIdx.x * 64;
  int tid = threadIdx.x;
  int r = tid >> 2, cg = (tid & 3) * 16;
  const float* rp = ip + (size_t)r * C + cg;
#pragma unroll
  for (int j = 0; j < 4; ++j) {
    float4 v = *(const float4*)(rp + j * 4);
    int c = cg + j * 4;
    t[c + 0][r] = f2bf(v.x);
    t[c + 1][r] = f2bf(v.y);
    t[c + 2][r] = f2bf(v.z);
    t[c + 3][r] = f2bf(v.w);
  }
  __syncthreads();
  int cr = tid >> 2, kg = (tid & 3) * 16;
  unsigned short* op = out + ((size_t)blockIdx.z * C + blockIdx.x * 64 + cr) * R +
                       blockIdx.y * 64 + kg;
  *(short8*)op = *(const short8*)&t[cr][kg];
  *(short8*)(op + 8) = *(const short8*)&t[cr][kg + 8];
}

// ============ GEMM1: DMA-staged, 4-buffer depth-3 pipeline (round-7 best) ============
__global__ __launch_bounds__(256) void gemm1_kernel(const unsigned short* __restrict__ Xb,
                                                    const unsigned short* __restrict__ w1t,
                                                    const int* __restrict__ tok,
                                                    const int* __restrict__ rowptr,
                                                    unsigned short* __restrict__ hbuf) {
  int f = blockIdx.x + 22 * blockIdx.y;
  int g = (f & 7) * 88 + (f >> 3);          // XCD-chunked bijective remap (704 % 8 == 0)
  int ftile = g >> 5, mtile = g & 31;
  int e = blockIdx.z;
  int base = rowptr[e], cnt = rowptr[e + 1] - base;
  if (mtile * 128 >= cnt) return;
  __shared__ char smem[4 * BUF];            // per buf: A at +0 (8KB), B at +8192 (8KB)
  int tid = threadIdx.x, lane = tid & 63, wave = tid >> 6;

  int rA = wave * 32 + (lane >> 2);
  int cd = (lane & 3) ^ ((rA >> 1) & 3);    // pre-swizzled global source chunk
  int sA0 = min(mtile * 128 + rA, cnt - 1);
  int sA1 = min(mtile * 128 + rA + 16, cnt - 1);
  const unsigned short* gA0 = Xb + (size_t)tok[base + sA0] * HID + cd * 8;
  const unsigned short* gA1 = Xb + (size_t)tok[base + sA1] * HID + cd * 8;
  int r1 = rA + 16;
  int p0 = (rA >> 4) & 1, f0 = (rA & 15) + 16 * (rA >> 5);
  int p1 = (r1 >> 4) & 1, f1 = (r1 & 15) + 16 * (r1 >> 5);
  const unsigned short* gB0 = w1t + ((size_t)(e * 2 + p0) * FF + ftile * 64 + f0) * HID + cd * 8;
  const unsigned short* gB1 = w1t + ((size_t)(e * 2 + p1) * FF + ftile * 64 + f1) * HID + cd * 8;
  int lb = wave * 2048 + lane * 16;          // linear DMA dest within A/B region

#define STG1(bp, k0) do {                          \
    gload16(gA0 + (k0), (bp) + lb);                \
    gload16(gA1 + (k0), (bp) + lb + 1024);         \
    gload16(gB0 + (k0), (bp) + 8192 + lb);         \
    gload16(gB1 + (k0), (bp) + 8192 + lb + 1024);  \
  } while (0)

  int wm = wave >> 1, wn = wave & 1, kc = lane >> 4;
  int aoff[4], boff[4];
#pragma unroll
  for (int mi = 0; mi < 4; ++mi) {
    int row = wm * 64 + mi * 16 + (lane & 15);
    aoff[mi] = row * 64 + ((kc ^ ((row >> 1) & 3)) << 4);
  }
#pragma unroll
  for (int ni = 0; ni < 4; ++ni) {
    int n = wn * 64 + ni * 16 + (lane & 15);
    boff[ni] = 8192 + n * 64 + ((kc ^ ((n >> 1) & 3)) << 4);
  }

  const f32x4 vz = {0.f, 0.f, 0.f, 0.f};
  f32x4 acc[4][4];
#pragma unroll
  for (int mi = 0; mi < 4; ++mi)
#pragma unroll
    for (int ni = 0; ni < 4; ++ni) acc[mi][ni] = vz;

  STG1(smem, 0);
  STG1(smem + BUF, 32);
  STG1(smem + 2 * BUF, 64);
  wait8_barrier();

  for (int t = 0; t < NT1; ++t) {
    char* cur = smem + (t & 3) * BUF;
    bool pf = (t + 3) < NT1;
    if (pf) STG1(smem + ((t + 3) & 3) * BUF, (t + 3) * 32);
    short8 af[4], bb[4];
#pragma unroll
    for (int mi = 0; mi < 4; ++mi) af[mi] = *(const short8*)(cur + aoff[mi]);
#pragma unroll
    for (int ni = 0; ni < 4; ++ni) bb[ni] = *(const short8*)(cur + boff[ni]);
    __builtin_amdgcn_s_setprio(1);
#pragma unroll
    for (int mi = 0; mi < 4; ++mi)
#pragma unroll
      for (int ni = 0; ni < 4; ++ni)
        acc[mi][ni] = __builtin_amdgcn_mfma_f32_16x16x32_bf16(af[mi], bb[ni], acc[mi][ni], 0, 0, 0);
    __builtin_amdgcn_s_setprio(0);
    if (pf) wait8_barrier();
    else if (t + 2 < NT1) wait4_barrier();
    else wait0_barrier();
  }
#undef STG1

  // epilogue: SwiGLU thread-local (acc[mi][0,2]=gate, acc[mi][1,3]=up at f, f+16)
  int fb = ftile * 64 + wn * 32 + (lane & 15);
#pragma unroll
  for (int mi = 0; mi < 4; ++mi) {
#pragma unroll
    for (int i = 0; i < 4; ++i) {
      int ml = wm * 64 + mi * 16 + (lane >> 4) * 4 + i;
      int slot = mtile * 128 + ml;
      if (slot < cnt) {
        size_t hrow = (size_t)(base + slot) * FF + fb;
        float g0 = acc[mi][0][i], u0 = acc[mi][1][i];
        float g1 = acc[mi][2][i], u1 = acc[mi][3][i];
        hbuf[hrow]      = f2bf(g0 / (1.f + __expf(-g0)) * u0);
        hbuf[hrow + 16] = f2bf(g1 / (1.f + __expf(-g1)) * u1);
      }
    }
  }
}

// ==== GEMM2: depth-2 pipeline (round-6 core), DENSE f32 stores (no atomics) ====
// obuf[slot][HID] = h W2; coef applied later in combine_kernel.
__global__ __launch_bounds__(256) void gemm2_kernel(const unsigned short* __restrict__ hbuf,
                                                    const unsigned short* __restrict__ w2t,
                                                    const int* __restrict__ rowptr,
                                                    float* __restrict__ obuf) {
  int f = blockIdx.x + 16 * blockIdx.y;
  int g = (f & 7) * 64 + (f >> 3);
  int ntile = g >> 5, mtile = g & 31;
  int e = blockIdx.z;
  int base = rowptr[e], cnt = rowptr[e + 1] - base;
  if (mtile * 128 >= cnt) return;
  __shared__ char smem[3 * BUF];
  int tid = threadIdx.x, lane = tid & 63, wave = tid >> 6;

  int rA = wave * 32 + (lane >> 2);
  int cd = (lane & 3) ^ ((rA >> 1) & 3);
  int sA0 = min(mtile * 128 + rA, cnt - 1);
  int sA1 = min(mtile * 128 + rA + 16, cnt - 1);
  const unsigned short* gA0 = hbuf + (size_t)(base + sA0) * FF + cd * 8;
  const unsigned short* gA1 = hbuf + (size_t)(base + sA1) * FF + cd * 8;
  const unsigned short* gB0 = w2t + ((size_t)e * HID + ntile * 128 + rA) * FF + cd * 8;
  const unsigned short* gB1 = gB0 + (size_t)16 * FF;
  int lb = wave * 2048 + lane * 16;

#define STG2(bp, k0) do {                          \
    gload16(gA0 + (k0), (bp) + lb);                \
    gload16(gA1 + (k0), (bp) + lb + 1024);         \
    gload16(gB0 + (k0), (bp) + 8192 + lb);         \
    gload16(gB1 + (k0), (bp) + 8192 + lb + 1024);  \
  } while (0)

  int wm = wave >> 1, wn = wave & 1, kc = lane >> 4;
  int aoff[4], boff[4];
#pragma unroll
  for (int mi = 0; mi < 4; ++mi) {
    int row = wm * 64 + mi * 16 + (lane & 15);
    aoff[mi] = row * 64 + ((kc ^ ((row >> 1) & 3)) << 4);
  }
#pragma unroll
  for (int ni = 0; ni < 4; ++ni) {
    int n = wn * 64 + ni * 16 + (lane & 15);
    boff[ni] = 8192 + n * 64 + ((kc ^ ((n >> 1) & 3)) << 4);
  }

  const f32x4 vz = {0.f, 0.f, 0.f, 0.f};
  f32x4 acc[4][4];
#pragma unroll
  for (int mi = 0; mi < 4; ++mi)
#pragma unroll
    for (int ni = 0; ni < 4; ++ni) acc[mi][ni] = vz;

  STG2(smem, 0);
  STG2(smem + BUF, 32);
  wait4_barrier();

  char* cur = smem;
  char* nxt = smem + 2 * BUF;
  for (int t = 0; t < NT2; ++t) {
    bool pf = (t + 2) < NT2;
    if (pf) STG2(nxt, (t + 2) * 32);
    short8 af[4], bb[4];
#pragma unroll
    for (int mi = 0; mi < 4; ++mi) af[mi] = *(const short8*)(cur + aoff[mi]);
#pragma unroll
    for (int ni = 0; ni < 4; ++ni) bb[ni] = *(const short8*)(cur + boff[ni]);
    __builtin_amdgcn_s_setprio(1);
#pragma unroll
    for (int mi = 0; mi < 4; ++mi)
#pragma unroll
      for (int ni = 0; ni < 4; ++ni)
        acc[mi][ni] = __builtin_amdgcn_mfma_f32_16x16x32_bf16(af[mi], bb[ni], acc[mi][ni], 0, 0, 0);
    __builtin_amdgcn_s_setprio(0);
    if (pf) wait4_barrier(); else wait0_barrier();
    cur = (cur == smem + 2 * BUF) ? smem : cur + BUF;
    nxt = (nxt == smem + 2 * BUF) ? smem : nxt + BUF;
  }
#undef STG2

  int nb = ntile * 128 + wn * 64 + (lane & 15);
#pragma unroll
  for (int mi = 0; mi < 4; ++mi) {
#pragma unroll
    for (int i = 0; i < 4; ++i) {
      int ml = wm * 64 + mi * 16 + (lane >> 4) * 4 + i;
      int slot = mtile * 128 + ml;
      if (slot < cnt) {
        float* op = obuf + (size_t)(base + slot) * HID + nb;
#pragma unroll
        for (int ni = 0; ni < 4; ++ni) op[ni * 16] = acc[mi][ni][i];
      }
    }
  }
}

// ---- combine: out[t] = coef[p0]*obuf[p0] + coef[p1]*obuf[p1] (fully coalesced) ----
__global__ __launch_bounds__(256) void combine_kernel(const float* __restrict__ obuf,
                                                      const int2* __restrict__ invm,
                                                      const float* __restrict__ coef,
                                                      float* __restrict__ out) {
  int idx = blockIdx.x * 256 + threadIdx.x;
  int t = idx >> 9, h4 = idx & 511;          // HID/4 = 512 float4 per row
  int2 pp = invm[t];
  float c0 = coef[pp.x], c1 = coef[pp.y];
  float4 a = ((const float4*)(obuf + (size_t)pp.x * HID))[h4];
  float4 b = ((const float4*)(obuf + (size_t)pp.y * HID))[h4];
  float4 o;
  o.x = c0 * a.x + c1 * b.x;
  o.y = c0 * a.y + c1 * b.y;
  o.z = c0 * a.z + c1 * b.z;
  o.w = c0 * a.w + c1 * b.w;
  ((float4*)out)[idx] = o;
}

// ---- fallback gemm2 (round-6, atomic epilogue) for small workspace ----
__global__ __launch_bounds__(256) void gemm2_atomic(const unsigned short* __restrict__ hbuf,
                                                    const unsigned short* __restrict__ w2t,
                                                    const int* __restrict__ tok,
                                                    const float* __restrict__ coef,
                                                    const int* __restrict__ rowptr,
                                                    float* __restrict__ out) {
  int f = blockIdx.x + 16 * blockIdx.y;
  int g = (f & 7) * 64 + (f >> 3);
  int ntile = g >> 5, mtile = g & 31;
  int e = blockIdx.z;
  int base = rowptr[e], cnt = rowptr[e + 1] - base;
  if (mtile * 128 >= cnt) return;
  __shared__ char smem[3 * BUF];
  __shared__ int tokL[128];
  __shared__ float cofL[128];
  int tid = threadIdx.x, lane = tid & 63, wave = tid >> 6;
  if (tid < 128) {
    int slot = min(mtile * 128 + tid, cnt - 1);
    tokL[tid] = tok[base + slot];
    cofL[tid] = coef[base + slot];
  }
  __syncthreads();

  int rA = wave * 32 + (lane >> 2);
  int cd = (lane & 3) ^ ((rA >> 1) & 3);
  int sA0 = min(mtile * 128 + rA, cnt - 1);
  int sA1 = min(mtile * 128 + rA + 16, cnt - 1);
  const unsigned short* gA0 = hbuf + (size_t)(base + sA0) * FF + cd * 8;
  const unsigned short* gA1 = hbuf + (size_t)(base + sA1) * FF + cd * 8;
  const unsigned short* gB0 = w2t + ((size_t)e * HID + ntile * 128 + rA) * FF + cd * 8;
  const unsigned short* gB1 = gB0 + (size_t)16 * FF;
  int lb = wave * 2048 + lane * 16;

#define STG2F(bp, k0) do {                         \
    gload16(gA0 + (k0), (bp) + lb);                \
    gload16(gA1 + (k0), (bp) + lb + 1024);         \
    gload16(gB0 + (k0), (bp) + 8192 + lb);         \
    gload16(gB1 + (k0), (bp) + 8192 + lb + 1024);  \
  } while (0)

  int wm = wave >> 1, wn = wave & 1, kc = lane >> 4;
  int aoff[4], boff[4];
#pragma unroll
  for (int mi = 0; mi < 4; ++mi) {
    int row = wm * 64 + mi * 16 + (lane & 15);
    aoff[mi] = row * 64 + ((kc ^ ((row >> 1) & 3)) << 4);
  }
#pragma unroll
  for (int ni = 0; ni < 4; ++ni) {
    int n = wn * 64 + ni * 16 + (lane & 15);
    boff[ni] = 8192 + n * 64 + ((kc ^ ((n >> 1) & 3)) << 4);
  }

  const f32x4 vz = {0.f, 0.f, 0.f, 0.f};
  f32x4 acc[4][4];
#pragma unroll
  for (int mi = 0; mi < 4; ++mi)
#pragma unroll
    for (int ni = 0; ni < 4; ++ni) acc[mi][ni] = vz;

  STG2F(smem, 0);
  STG2F(smem + BUF, 32);
  wait4_barrier();

  char* cur = smem;
  char* nxt = smem + 2 * BUF;
  for (int t = 0; t < NT2; ++t) {
    bool pf = (t + 2) < NT2;
    if (pf) STG2F(nxt, (t + 2) * 32);
    short8 af[4], bb[4];
#pragma unroll
    for (int mi = 0; mi < 4; ++mi) af[mi] = *(const short8*)(cur + aoff[mi]);
#pragma unroll
    for (int ni = 0; ni < 4; ++ni) bb[ni] = *(const short8*)(cur + boff[ni]);
    __builtin_amdgcn_s_setprio(1);
#pragma unroll
    for (int mi = 0; mi < 4; ++mi)
#pragma unroll
      for (int ni = 0; ni < 4; ++ni)
        acc[mi][ni] = __builtin_amdgcn_mfma_f32_16x16x32_bf16(af[mi], bb[ni], acc[mi][ni], 0, 0, 0);
    __builtin_amdgcn_s_setprio(0);
    if (pf) wait4_barrier(); else wait0_barrier();
    cur = (cur == smem + 2 * BUF) ? smem : cur + BUF;
    nxt = (nxt == smem + 2 * BUF) ? smem : nxt + BUF;
  }
#undef STG2F

#pragma unroll
  for (int mi = 0; mi < 4; ++mi) {
#pragma unroll
    for (int i = 0; i < 4; ++i) {
      int ml = wm * 64 + mi * 16 + (lane >> 4) * 4 + i;
      int slot = mtile * 128 + ml;
      if (slot < cnt) {
        float cf = cofL[ml];
        float* op = out + (size_t)tokL[ml] * HID + ntile * 128 + wn * 64 + (lane & 15);
#pragma unroll
        for (int ni = 0; ni < 4; ++ni)
          unsafeAtomicAdd(op + ni * 16, cf * acc[mi][ni][i]);
      }
    }
  }
}

extern "C" void kernel_launch(void* const* d_in, const int* in_sizes, int n_in,
                              void* d_out, int out_size, void* d_ws, size_t ws_size,
                              hipStream_t stream) {
  const float* X  = (const float*)d_in[0];
  const float* RL = (const float*)d_in[1];
  const float* W1 = (const float*)d_in[2];
  const float* W2 = (const float*)d_in[3];
  float* out = (float*)d_out;

  const size_t OFF_EIDS = 4096;
  const size_t OFF_ECFS = 36864;
  const size_t OFF_TOK  = 69632;
  const size_t OFF_COEF = 102400;
  const size_t OFF_XB   = 135168;
  const size_t OFF_H    = 16912384;
  const size_t OFF_W1T  = 39981056;
  const size_t OFF_W2T  = 132255744;
  const size_t TOTAL2   = 178393088;       // proven available (rounds 4-8)
  const size_t OFF_INV  = 178393088;       // +32KB inverse map (guarded)
  const size_t TOTAL3   = 178425856;
  if (ws_size < TOTAL2 || n_in < 4) return;
  bool big = ws_size >= TOTAL3;

  char* w = (char*)d_ws;
  int*    rowptr = (int*)w;
  int2*   eids   = (int2*)(w + OFF_EIDS);
  float2* ecfs   = (float2*)(w + OFF_ECFS);
  int*    tok    = (int*)(w + OFF_TOK);
  float*  coef   = (float*)(w + OFF_COEF);
  unsigned short* Xb   = (unsigned short*)(w + OFF_XB);
  unsigned short* hbuf = (unsigned short*)(w + OFF_H);
  unsigned short* w1t  = (unsigned short*)(w + OFF_W1T);
  unsigned short* w2t  = (unsigned short*)(w + OFF_W2T);
  // obuf aliases w1t (dead after gemm1; rewritten by wcvt every launch).
  float* obuf = (float*)(w + OFF_W1T);
  // small-ws fallback: inv writes land in hbuf scratch (overwritten by gemm1, unused)
  int* invm = big ? (int*)(w + OFF_INV) : (int*)hbuf;

  if (!big) hipMemsetAsync(d_out, 0, (size_t)T_TOK * HID * sizeof(float), stream);
  route_kernel<<<T_TOK / 256, 256, 0, stream>>>(RL, eids, ecfs);
  compact_kernel<<<NE, 256, 0, stream>>>(eids, ecfs, tok, coef, rowptr, invm);
  cvtx_kernel<<<(T_TOK * HID / 4) / 256, 256, 0, stream>>>(X, Xb);
  // w1[e*2+g][k=2048][f=1408] -> w1t[e*2+g][f][k]
  wcvt_kernel<<<dim3(FF / 64, HID / 64, NE * 2), 256, 0, stream>>>(W1, w1t, HID, FF);
  // w2[e][f=1408][h=2048] -> w2t[e][h][f]
  wcvt_kernel<<<dim3(HID / 64, FF / 64, NE), 256, 0, stream>>>(W2, w2t, FF, HID);
  gemm1_kernel<<<dim3(FF / 64, T_TOK / 128, NE), 256, 0, stream>>>(Xb, w1t, tok, rowptr, hbuf);
  if (big) {
    gemm2_kernel<<<dim3(HID / 128, T_TOK / 128, NE), 256, 0, stream>>>(hbuf, w2t, rowptr, obuf);
    combine_kernel<<<(T_TOK * HID / 4) / 256, 256, 0, stream>>>(obuf, (const int2*)invm, coef, out);
  } else {
    gemm2_atomic<<<dim3(HID / 128, T_TOK / 128, NE), 256, 0, stream>>>(hbuf, w2t, tok, coef, rowptr, out);
  }
}